// Round 6
// baseline (315.781 us; speedup 1.0000x reference)
//
#include <hip/hip_runtime.h>
#include <hip/hip_bf16.h>
#include <stdint.h>
#include <stddef.h>

#define B_   8
#define N_   256
#define H_   128
#define E_   128
#define INZ  256
#define BIGN 1000000.0f

// DIAGNOSTIC ROUND: pgn_main repeats its i-loop REPEAT_ times (idempotent max)
// so it exceeds the harness's 155us fill kernels and shows up in rocprof
// top-5 WITH counters. Result is bit-identical to REPEAT_=1.
#define REPEAT_ 4

typedef float f32x4 __attribute__((ext_vector_type(4)));
typedef short bf16x8 __attribute__((ext_vector_type(8)));

static __device__ __forceinline__ unsigned cvt2(float a, float b) {
    unsigned short ra = __builtin_bit_cast(unsigned short, __float2bfloat16(a));
    unsigned short rb = __builtin_bit_cast(unsigned short, __float2bfloat16(b));
    return (unsigned)ra | ((unsigned)rb << 16);
}

static __device__ __forceinline__ bf16x8 mk_frag(f32x4 lo, f32x4 h4) {
    union { unsigned u[4]; bf16x8 v; } r;
    r.u[0] = cvt2(lo.x, lo.y);
    r.u[1] = cvt2(lo.z, lo.w);
    r.u[2] = cvt2(h4.x, h4.y);
    r.u[3] = cvt2(h4.z, h4.w);
    return r.v;
}

// ---------------------------------------------------------------------------
// prep: msg1 = z@W1+b1 ; m2g = z@W2+b2+graph@Wg+bg ; zo1 = z@Wo1+bo1
// blocks 0..7 also produce We^T -> bf16 LINEAR [e][k]
// ---------------------------------------------------------------------------
__global__ __launch_bounds__(256) void prep_kernel(
    const float* __restrict__ node, const float* __restrict__ hidden,
    const float* __restrict__ gf,
    const float* __restrict__ W1, const float* __restrict__ b1,
    const float* __restrict__ W2, const float* __restrict__ b2,
    const float* __restrict__ Wg, const float* __restrict__ bg,
    const float* __restrict__ Wo1, const float* __restrict__ bo1,
    const float* __restrict__ We,
    float* __restrict__ msg1, float* __restrict__ m2g,
    float* __restrict__ zo1, unsigned short* __restrict__ weT)
{
    __shared__ float zs[4][INZ];
    const int t  = threadIdx.x;
    const int r0 = blockIdx.x * 4;
    const int b  = r0 >> 8;

    for (int idx = t; idx < 4 * INZ; idx += 256) {
        int r = idx >> 8, k = idx & 255;
        int row = r0 + r;
        zs[r][k] = (k < H_) ? node[(size_t)row * H_ + k]
                            : hidden[(size_t)row * H_ + (k - H_)];
    }
    if (blockIdx.x < 8) {
        int e0 = blockIdx.x * 2048;
        for (int e = e0 + t; e < e0 + 2048; e += 256) {
            int n = e >> 7, k = e & 127;   // weT[e_col][k]
            weT[e] = (unsigned short)__builtin_bit_cast(unsigned short,
                         __float2bfloat16(We[k * 128 + n]));
        }
    }
    __syncthreads();

    const int col = t & 127;
    const int rg  = t >> 7;
    float a1[2] = {0, 0}, a2[2] = {0, 0}, ao[2] = {0, 0};

#pragma unroll 4
    for (int k = 0; k < INZ; ++k) {
        float w1 = W1[k * 128 + col];
        float w2 = W2[k * 128 + col];
        float wo = Wo1[k * 128 + col];
#pragma unroll
        for (int rr = 0; rr < 2; ++rr) {
            float zv = zs[rg * 2 + rr][k];
            a1[rr] = fmaf(zv, w1, a1[rr]);
            a2[rr] = fmaf(zv, w2, a2[rr]);
            ao[rr] = fmaf(zv, wo, ao[rr]);
        }
    }
    float mg = bg[col];
#pragma unroll 4
    for (int g = 0; g < 128; ++g)
        mg = fmaf(gf[b * 128 + g], Wg[g * 128 + col], mg);

    const float bb1 = b1[col], bb2 = b2[col], bbo = bo1[col];
#pragma unroll
    for (int rr = 0; rr < 2; ++rr) {
        size_t row = (size_t)(r0 + rg * 2 + rr);
        msg1[row * 128 + col] = a1[rr] + bb1;
        m2g[row * 128 + col]  = a2[rr] + bb2 + mg;
        zo1[row * 128 + col]  = ao[rr] + bbo;
    }
}

// ---------------------------------------------------------------------------
// main (R5 structure, REPEAT_x instrumented): 512 blocks = (b, ic, jq).
// GEMM rows = j; A direct global->VGPR, B (WeT) in 128 VGPRs, no LDS/barriers.
// ---------------------------------------------------------------------------
__global__ __launch_bounds__(256, 2) void pgn_main(
    const float* __restrict__ edge, const float* __restrict__ adj,
    const float* __restrict__ m2g, const unsigned short* __restrict__ weT,
    float* __restrict__ redp)
{
    const int t    = threadIdx.x;
    const int lane = t & 63, wid = t >> 6;
    const int hi   = lane >> 4, c15 = lane & 15;
    const int blk  = blockIdx.x;
    const int b    = blk >> 6;
    const int ic   = (blk >> 2) & 15;
    const int jq   = blk & 3;
    const int i0   = ic * 16;
    const int jrow = jq * 64 + wid * 16 + c15;

    bf16x8 bfr[8][4];
#pragma unroll
    for (int n = 0; n < 8; ++n) {
#pragma unroll
        for (int ks = 0; ks < 4; ++ks)
            bfr[n][ks] = *(const bf16x8*)(weT + (n * 16 + c15) * 128 + ks * 32 + hi * 8);
    }

    float rmax[8][4];
#pragma unroll
    for (int n = 0; n < 8; ++n)
#pragma unroll
        for (int rg = 0; rg < 4; ++rg) rmax[n][rg] = -BIGN;

    const float* abase = edge + ((size_t)(b * N_ + i0) * N_ + jrow) * E_ + hi * 8;
    const float* adjb  = adj + (size_t)(b * N_ + i0) * N_ + jq * 64 + wid * 16 + hi * 4;
    const float* m2gb  = m2g + (size_t)(b * N_ + i0) * 128 + c15;

    for (int rep = 0; rep < REPEAT_; ++rep) {
        // memory clobber: forbids CSE of loads across passes -> real re-reads
        asm volatile("" ::: "memory");
#pragma unroll 2
        for (int ii = 0; ii < 16; ++ii) {
            const float* ar = abase + (size_t)ii * (N_ * E_);

            f32x4 a4 = *(const f32x4*)(adjb + (size_t)ii * N_);
            float mv[8];
#pragma unroll
            for (int n = 0; n < 8; ++n) mv[n] = m2gb[(size_t)ii * 128 + n * 16];

            f32x4 acc[8] = {};
#pragma unroll
            for (int ks = 0; ks < 4; ++ks) {
                f32x4 lo = *(const f32x4*)(ar + ks * 32);
                f32x4 h4 = *(const f32x4*)(ar + ks * 32 + 4);
                bf16x8 af = mk_frag(lo, h4);
#pragma unroll
                for (int n = 0; n < 8; ++n)
                    acc[n] = __builtin_amdgcn_mfma_f32_16x16x32_bf16(
                        af, bfr[n][ks], acc[n], 0, 0, 0);
            }

#pragma unroll
            for (int n = 0; n < 8; ++n)
#pragma unroll
                for (int rg = 0; rg < 4; ++rg) {
                    float v = acc[n][rg] + mv[n];
                    v = (a4[rg] > 0.0f) ? v : -BIGN;
                    rmax[n][rg] = fmaxf(rmax[n][rg], v);
                }
        }
    }

    float* rp = redp + (size_t)blk * 8192;
#pragma unroll
    for (int n = 0; n < 8; ++n)
#pragma unroll
        for (int rg = 0; rg < 4; ++rg) {
            int jl = wid * 16 + hi * 4 + rg;
            rp[jl * 128 + n * 16 + c15] = rmax[n][rg];
        }
}

// ---------------------------------------------------------------------------
// finish: red = max over 16 i-chunks; out = relu(zo1 + (red+msg1+be)@Wo2+bo2)
// ---------------------------------------------------------------------------
__global__ __launch_bounds__(256) void finish_kernel(
    const float* __restrict__ redp, const float* __restrict__ msg1,
    const float* __restrict__ zo1, const float* __restrict__ be,
    const float* __restrict__ Wo2, const float* __restrict__ bo2,
    float* __restrict__ out)
{
    __shared__ float rb[8][128];
    const int t  = threadIdx.x;
    const int r0 = blockIdx.x * 8;

    for (int idx = t; idx < 1024; idx += 256) {
        int rr = idx >> 7, k = idx & 127;
        int r  = r0 + rr;
        int b  = r >> 8, j = r & 255;
        int jq = j >> 6, jl = j & 63;
        float v = -BIGN - 1.0f;
#pragma unroll 4
        for (int ic = 0; ic < 16; ++ic)
            v = fmaxf(v, redp[(size_t)(((b * 16 + ic) * 4) + jq) * 8192 + jl * 128 + k]);
        rb[rr][k] = v + msg1[(size_t)r * 128 + k] + be[k];
    }
    __syncthreads();

    const int col  = t & 127;
    const int half = t >> 7;
#pragma unroll
    for (int rx = 0; rx < 4; ++rx) {
        int rr = half * 4 + rx;
        size_t row = (size_t)(r0 + rr);
        float a = 0.0f;
#pragma unroll 8
        for (int k = 0; k < 128; ++k)
            a = fmaf(rb[rr][k], Wo2[k * 128 + col], a);
        float o = zo1[row * 128 + col] + bo2[col] + a;
        out[row * 128 + col] = fmaxf(o, 0.0f);
    }
}

extern "C" void kernel_launch(void* const* d_in, const int* in_sizes, int n_in,
                              void* d_out, int out_size, void* d_ws, size_t ws_size,
                              hipStream_t stream) {
    const float* node   = (const float*)d_in[0];
    const float* edge   = (const float*)d_in[1];
    const float* gf     = (const float*)d_in[2];
    const float* adj    = (const float*)d_in[3];
    const float* hidden = (const float*)d_in[4];
    const float* W1  = (const float*)d_in[5];
    const float* b1  = (const float*)d_in[6];
    const float* W2  = (const float*)d_in[7];
    const float* b2  = (const float*)d_in[8];
    const float* We  = (const float*)d_in[9];
    const float* be  = (const float*)d_in[10];
    const float* Wg  = (const float*)d_in[11];
    const float* bg  = (const float*)d_in[12];
    const float* Wo1 = (const float*)d_in[13];
    const float* bo1 = (const float*)d_in[14];
    const float* Wo2 = (const float*)d_in[15];
    const float* bo2 = (const float*)d_in[16];
    float* out = (float*)d_out;

    float* msg1 = (float*)d_ws;                                   // 1 MB
    float* m2g  = msg1 + 2048 * 128;                              // 1 MB
    float* zo1  = m2g + 2048 * 128;                               // 1 MB
    unsigned short* weT = (unsigned short*)(zo1 + 2048 * 128);    // 32 KB
    float* redp = (float*)((char*)weT + 128 * 128 * sizeof(unsigned short)); // 16 MB

    hipLaunchKernelGGL(prep_kernel, dim3(512), dim3(256), 0, stream,
                       node, hidden, gf, W1, b1, W2, b2, Wg, bg, Wo1, bo1, We,
                       msg1, m2g, zo1, weT);
    hipLaunchKernelGGL(pgn_main, dim3(512), dim3(256), 0, stream,
                       edge, adj, m2g, weT, redp);
    hipLaunchKernelGGL(finish_kernel, dim3(256), dim3(256), 0, stream,
                       redp, msg1, zo1, be, Wo2, bo2, out);
}

// Round 7
// 231.778 us; speedup vs baseline: 1.3624x; 1.3624x over previous
//
#include <hip/hip_runtime.h>
#include <hip/hip_bf16.h>
#include <stdint.h>
#include <stddef.h>

#define B_   8
#define N_   256
#define H_   128
#define E_   128
#define INZ  256
#define BIGN 1000000.0f

typedef float f32x4 __attribute__((ext_vector_type(4)));
typedef short bf16x8 __attribute__((ext_vector_type(8)));

static __device__ __forceinline__ unsigned cvt2(float a, float b) {
    unsigned short ra = __builtin_bit_cast(unsigned short, __float2bfloat16(a));
    unsigned short rb = __builtin_bit_cast(unsigned short, __float2bfloat16(b));
    return (unsigned)ra | ((unsigned)rb << 16);
}

static __device__ __forceinline__ bf16x8 mk_frag(f32x4 lo, f32x4 h4) {
    union { unsigned u[4]; bf16x8 v; } r;
    r.u[0] = cvt2(lo.x, lo.y);
    r.u[1] = cvt2(lo.z, lo.w);
    r.u[2] = cvt2(h4.x, h4.y);
    r.u[3] = cvt2(h4.z, h4.w);
    return r.v;
}

// ---------------------------------------------------------------------------
// prep: msg1 = z@W1+b1 ; m2g = z@W2+b2+graph@Wg+bg ; zo1 = z@Wo1+bo1
// blocks 0..7 also produce We^T -> bf16, XOR-pre-swizzled (R1 layout):
//   weT[(n*128 + k) ^ ((n&7)<<3)] = bf16(We[k][n])
// ---------------------------------------------------------------------------
__global__ __launch_bounds__(256) void prep_kernel(
    const float* __restrict__ node, const float* __restrict__ hidden,
    const float* __restrict__ gf,
    const float* __restrict__ W1, const float* __restrict__ b1,
    const float* __restrict__ W2, const float* __restrict__ b2,
    const float* __restrict__ Wg, const float* __restrict__ bg,
    const float* __restrict__ Wo1, const float* __restrict__ bo1,
    const float* __restrict__ We,
    float* __restrict__ msg1, float* __restrict__ m2g,
    float* __restrict__ zo1, unsigned short* __restrict__ weT)
{
    __shared__ float zs[4][INZ];
    const int t  = threadIdx.x;
    const int r0 = blockIdx.x * 4;
    const int b  = r0 >> 8;

    for (int idx = t; idx < 4 * INZ; idx += 256) {
        int r = idx >> 8, k = idx & 255;
        int row = r0 + r;
        zs[r][k] = (k < H_) ? node[(size_t)row * H_ + k]
                            : hidden[(size_t)row * H_ + (k - H_)];
    }
    if (blockIdx.x < 8) {
        int e0 = blockIdx.x * 2048;
        for (int e = e0 + t; e < e0 + 2048; e += 256) {
            int n = e >> 7, k = e & 127;
            weT[(n * 128 + k) ^ ((n & 7) << 3)] =
                (unsigned short)__builtin_bit_cast(unsigned short,
                    __float2bfloat16(We[k * 128 + n]));
        }
    }
    __syncthreads();

    const int col = t & 127;
    const int rg  = t >> 7;
    float a1[2] = {0, 0}, a2[2] = {0, 0}, ao[2] = {0, 0};

#pragma unroll 4
    for (int k = 0; k < INZ; ++k) {
        float w1 = W1[k * 128 + col];
        float w2 = W2[k * 128 + col];
        float wo = Wo1[k * 128 + col];
#pragma unroll
        for (int rr = 0; rr < 2; ++rr) {
            float zv = zs[rg * 2 + rr][k];
            a1[rr] = fmaf(zv, w1, a1[rr]);
            a2[rr] = fmaf(zv, w2, a2[rr]);
            ao[rr] = fmaf(zv, wo, ao[rr]);
        }
    }
    float mg = bg[col];
#pragma unroll 4
    for (int g = 0; g < 128; ++g)
        mg = fmaf(gf[b * 128 + g], Wg[g * 128 + col], mg);

    const float bb1 = b1[col], bb2 = b2[col], bbo = bo1[col];
#pragma unroll
    for (int rr = 0; rr < 2; ++rr) {
        size_t row = (size_t)(r0 + rg * 2 + rr);
        msg1[row * 128 + col] = a1[rr] + bb1;
        m2g[row * 128 + col]  = a2[rr] + bb2 + mg;
        zo1[row * 128 + col]  = ao[rr] + bbo;
    }
}

// ---------------------------------------------------------------------------
// main: grid = 8b x (1<<icbits) i-chunks x 4 jq. 4 waves; wave owns 16 j-rows
// x all 128 e-cols. B panel in LDS (staged once, swizzled reads ~2-way);
// A direct global->VGPR in fragment order; rmax register-resident over i.
// No per-iteration barriers. 3-4 blocks/CU resident.
// ---------------------------------------------------------------------------
__global__ __launch_bounds__(256, 3) void pgn_main(
    const float* __restrict__ edge, const float* __restrict__ adj,
    const float* __restrict__ m2g, const unsigned short* __restrict__ weT,
    float* __restrict__ redp, int icbits)
{
    __shared__ __align__(16) short blds[128 * 128];   // 32KB B panel

    const int t    = threadIdx.x;
    const int lane = t & 63, wid = t >> 6;
    const int hi   = lane >> 4, c15 = lane & 15;
    const int blk  = blockIdx.x;
    const int jq   = blk & 3;
    const int ic   = (blk >> 2) & ((1 << icbits) - 1);
    const int b    = blk >> (icbits + 2);
    const int ni   = N_ >> icbits;
    const int i0   = ic * ni;
    const int jrow = jq * 64 + wid * 16 + c15;

    // ---- stage B panel (pre-swizzled weT) into LDS, linear 32KB copy ----
    {
        const uint4* ws = (const uint4*)weT;
        uint4* wd = (uint4*)blds;
#pragma unroll
        for (int q = 0; q < 8; ++q) wd[t + 256 * q] = ws[t + 256 * q];
    }

    float rmax[8][4];
#pragma unroll
    for (int n = 0; n < 8; ++n)
#pragma unroll
        for (int rg = 0; rg < 4; ++rg) rmax[n][rg] = -BIGN;

    const float* abase = edge + ((size_t)(b * N_ + i0) * N_ + jrow) * E_ + hi * 8;
    const float* adjb  = adj + (size_t)(b * N_ + i0) * N_ + jq * 64 + wid * 16 + hi * 4;
    const float* m2gb  = m2g + (size_t)(b * N_ + i0) * 128 + c15;

    // precompute swizzled B byte offsets (loop-invariant)
    int boff[8][4];
#pragma unroll
    for (int n = 0; n < 8; ++n) {
        int rowB = n * 16 + c15;
#pragma unroll
        for (int ks = 0; ks < 4; ++ks)
            boff[n][ks] = (rowB * 256 + ks * 64 + hi * 16) ^ ((rowB & 7) << 4);
    }

    __syncthreads();   // blds ready

#pragma unroll 2
    for (int ii = 0; ii < ni; ++ii) {
        const float* ar = abase + (size_t)ii * (N_ * E_);

        // ---- issue all A loads for this i up-front (8 x 16B in flight) ----
        f32x4 pf[8];
#pragma unroll
        for (int ks = 0; ks < 4; ++ks) {
            pf[2 * ks]     = *(const f32x4*)(ar + ks * 32);
            pf[2 * ks + 1] = *(const f32x4*)(ar + ks * 32 + 4);
        }
        f32x4 a4 = *(const f32x4*)(adjb + (size_t)ii * N_);
        float mv[8];
#pragma unroll
        for (int n = 0; n < 8; ++n) mv[n] = m2gb[(size_t)ii * 128 + n * 16];

        // ---- 16j x 128e x K=128: A from regs, B from LDS, 32 MFMA ----
        f32x4 acc[8] = {};
#pragma unroll
        for (int ks = 0; ks < 4; ++ks) {
            bf16x8 af = mk_frag(pf[2 * ks], pf[2 * ks + 1]);
#pragma unroll
            for (int n = 0; n < 8; ++n) {
                bf16x8 bv = *(const bf16x8*)((const char*)blds + boff[n][ks]);
                acc[n] = __builtin_amdgcn_mfma_f32_16x16x32_bf16(
                    af, bv, acc[n], 0, 0, 0);
            }
        }

        // ---- masked running max over i; C row (=j rem) = hi*4+rg ----
#pragma unroll
        for (int n = 0; n < 8; ++n)
#pragma unroll
            for (int rg = 0; rg < 4; ++rg) {
                float v = acc[n][rg] + mv[n];
                v = (a4[rg] > 0.0f) ? v : -BIGN;
                rmax[n][rg] = fmaxf(rmax[n][rg], v);
            }
    }

    // ---- write partial [64 j][128 e] ----
    float* rp = redp + (size_t)blk * 8192;
#pragma unroll
    for (int n = 0; n < 8; ++n)
#pragma unroll
        for (int rg = 0; rg < 4; ++rg) {
            int jl = wid * 16 + hi * 4 + rg;
            rp[jl * 128 + n * 16 + c15] = rmax[n][rg];
        }
}

// ---------------------------------------------------------------------------
// finish: red = max over i-chunks; out = relu(zo1 + (red+msg1+be)@Wo2 + bo2)
// ---------------------------------------------------------------------------
__global__ __launch_bounds__(256) void finish_kernel(
    const float* __restrict__ redp, const float* __restrict__ msg1,
    const float* __restrict__ zo1, const float* __restrict__ be,
    const float* __restrict__ Wo2, const float* __restrict__ bo2,
    float* __restrict__ out, int icbits)
{
    __shared__ float rb[8][128];
    const int t  = threadIdx.x;
    const int r0 = blockIdx.x * 8;
    const int S  = 1 << icbits;

    for (int idx = t; idx < 1024; idx += 256) {
        int rr = idx >> 7, k = idx & 127;
        int r  = r0 + rr;
        int b  = r >> 8, j = r & 255;
        int jq = j >> 6, jl = j & 63;
        float v = -BIGN - 1.0f;
        for (int p = 0; p < S; ++p)
            v = fmaxf(v, redp[(size_t)(((b << icbits) + p) * 4 + jq) * 8192
                              + jl * 128 + k]);
        rb[rr][k] = v + msg1[(size_t)r * 128 + k] + be[k];
    }
    __syncthreads();

    const int col  = t & 127;
    const int half = t >> 7;
#pragma unroll
    for (int rx = 0; rx < 4; ++rx) {
        int rr = half * 4 + rx;
        size_t row = (size_t)(r0 + rr);
        float a = 0.0f;
#pragma unroll 8
        for (int k = 0; k < 128; ++k)
            a = fmaf(rb[rr][k], Wo2[k * 128 + col], a);
        float o = zo1[row * 128 + col] + bo2[col] + a;
        out[row * 128 + col] = fmaxf(o, 0.0f);
    }
}

extern "C" void kernel_launch(void* const* d_in, const int* in_sizes, int n_in,
                              void* d_out, int out_size, void* d_ws, size_t ws_size,
                              hipStream_t stream) {
    const float* node   = (const float*)d_in[0];
    const float* edge   = (const float*)d_in[1];
    const float* gf     = (const float*)d_in[2];
    const float* adj    = (const float*)d_in[3];
    const float* hidden = (const float*)d_in[4];
    const float* W1  = (const float*)d_in[5];
    const float* b1  = (const float*)d_in[6];
    const float* W2  = (const float*)d_in[7];
    const float* b2  = (const float*)d_in[8];
    const float* We  = (const float*)d_in[9];
    const float* be  = (const float*)d_in[10];
    const float* Wg  = (const float*)d_in[11];
    const float* bg  = (const float*)d_in[12];
    const float* Wo1 = (const float*)d_in[13];
    const float* bo1 = (const float*)d_in[14];
    const float* Wo2 = (const float*)d_in[15];
    const float* bo2 = (const float*)d_in[16];
    float* out = (float*)d_out;

    float* msg1 = (float*)d_ws;                                   // 1 MB
    float* m2g  = msg1 + 2048 * 128;                              // 1 MB
    float* zo1  = m2g + 2048 * 128;                               // 1 MB
    unsigned short* weT = (unsigned short*)(zo1 + 2048 * 128);    // 32 KB
    float* redp = (float*)((char*)weT + 128 * 128 * sizeof(unsigned short));

    // icbits=5: 1024 blocks, redp 32MB (ws >= ~36MB); else icbits=4 (R5 size)
    const size_t fixed = 3u * 1048576u + 32768u;
    int icbits = (ws_size >= fixed + 33u * 1048576u) ? 5 : 4;
    int nblk   = 32 << icbits;

    hipLaunchKernelGGL(prep_kernel, dim3(512), dim3(256), 0, stream,
                       node, hidden, gf, W1, b1, W2, b2, Wg, bg, Wo1, bo1, We,
                       msg1, m2g, zo1, weT);
    hipLaunchKernelGGL(pgn_main, dim3(nblk), dim3(256), 0, stream,
                       edge, adj, m2g, weT, redp, icbits);
    hipLaunchKernelGGL(finish_kernel, dim3(256), dim3(256), 0, stream,
                       redp, msg1, zo1, be, Wo2, bo2, out, icbits);
}

// Round 8
// 107.227 us; speedup vs baseline: 2.9450x; 2.1616x over previous
//
#include <hip/hip_runtime.h>
#include <hip/hip_bf16.h>
#include <stdint.h>
#include <stddef.h>

#define B_   8
#define N_   256
#define H_   128
#define E_   128
#define INZ  256
#define BIGN 1000000.0f

typedef float f32x4 __attribute__((ext_vector_type(4)));
typedef short bf16x8 __attribute__((ext_vector_type(8)));

static __device__ __forceinline__ unsigned cvt2(float a, float b) {
    unsigned short ra = __builtin_bit_cast(unsigned short, __float2bfloat16(a));
    unsigned short rb = __builtin_bit_cast(unsigned short, __float2bfloat16(b));
    return (unsigned)ra | ((unsigned)rb << 16);
}

// ---------------------------------------------------------------------------
// prep: msg1 = z@W1+b1 ; m2g = z@W2+b2+graph@Wg+bg ; zo1 = z@Wo1+bo1
// blocks 0..7 also produce We^T -> bf16 LINEAR [e][k]
// ---------------------------------------------------------------------------
__global__ __launch_bounds__(256) void prep_kernel(
    const float* __restrict__ node, const float* __restrict__ hidden,
    const float* __restrict__ gf,
    const float* __restrict__ W1, const float* __restrict__ b1,
    const float* __restrict__ W2, const float* __restrict__ b2,
    const float* __restrict__ Wg, const float* __restrict__ bg,
    const float* __restrict__ Wo1, const float* __restrict__ bo1,
    const float* __restrict__ We,
    float* __restrict__ msg1, float* __restrict__ m2g,
    float* __restrict__ zo1, unsigned short* __restrict__ weT)
{
    __shared__ float zs[4][INZ];
    const int t  = threadIdx.x;
    const int r0 = blockIdx.x * 4;
    const int b  = r0 >> 8;

    for (int idx = t; idx < 4 * INZ; idx += 256) {
        int r = idx >> 8, k = idx & 255;
        int row = r0 + r;
        zs[r][k] = (k < H_) ? node[(size_t)row * H_ + k]
                            : hidden[(size_t)row * H_ + (k - H_)];
    }
    if (blockIdx.x < 8) {
        int e0 = blockIdx.x * 2048;
        for (int e = e0 + t; e < e0 + 2048; e += 256) {
            int n = e >> 7, k = e & 127;   // weT[e_col][k] linear
            weT[e] = (unsigned short)__builtin_bit_cast(unsigned short,
                         __float2bfloat16(We[k * 128 + n]));
        }
    }
    __syncthreads();

    const int col = t & 127;
    const int rg  = t >> 7;
    float a1[2] = {0, 0}, a2[2] = {0, 0}, ao[2] = {0, 0};

#pragma unroll 4
    for (int k = 0; k < INZ; ++k) {
        float w1 = W1[k * 128 + col];
        float w2 = W2[k * 128 + col];
        float wo = Wo1[k * 128 + col];
#pragma unroll
        for (int rr = 0; rr < 2; ++rr) {
            float zv = zs[rg * 2 + rr][k];
            a1[rr] = fmaf(zv, w1, a1[rr]);
            a2[rr] = fmaf(zv, w2, a2[rr]);
            ao[rr] = fmaf(zv, wo, ao[rr]);
        }
    }
    float mg = bg[col];
#pragma unroll 4
    for (int g = 0; g < 128; ++g)
        mg = fmaf(gf[b * 128 + g], Wg[g * 128 + col], mg);

    const float bb1 = b1[col], bb2 = b2[col], bbo = bo1[col];
#pragma unroll
    for (int rr = 0; rr < 2; ++rr) {
        size_t row = (size_t)(r0 + rg * 2 + rr);
        msg1[row * 128 + col] = a1[rr] + bb1;
        m2g[row * 128 + col]  = a2[rr] + bb2 + mg;
        zo1[row * 128 + col]  = ao[rr] + bbo;
    }
}

// ---------------------------------------------------------------------------
// main: grid = 8b x ICS x 16jt. Block: 16 j-rows x 128 e, i-chunk of ni.
// Per tile (2 i): stage 16KB f32 wave-contiguous -> bf16 swizzled LDS (8KB),
// each wave computes its own 32 e-cols (B frags = 32 VGPR from linear weT).
// Software-pipelined loads; raw s_barrier + lgkmcnt only (no vmcnt drain).
// 8KB LDS, ~115 VGPR, launch_bounds(256,4) -> 4 blocks/CU (16 waves/CU).
// ---------------------------------------------------------------------------
__global__ __launch_bounds__(256, 4) void pgn_main(
    const float* __restrict__ edge, const float* __restrict__ adj,
    const float* __restrict__ m2g, const unsigned short* __restrict__ weT,
    float* __restrict__ redp, int icsbits)
{
    __shared__ __align__(16) char atile[8192];   // [2 di][16 j][128 k] bf16

    const int t    = threadIdx.x;
    const int lane = t & 63, w = t >> 6;
    const int hi   = lane >> 4, c15 = lane & 15;
    const int blk  = blockIdx.x;
    const int jt   = blk & 15;
    const int ICS  = 1 << icsbits;
    const int ic   = (blk >> 4) & (ICS - 1);
    const int b    = blk >> (4 + icsbits);
    const int j0   = jt * 16;
    const int ni   = N_ >> icsbits;
    const int NT   = ni >> 1;
    const int i0   = ic * ni;

    // ---- B fragments: this wave's 32 e-cols, from linear weT [e][k] ----
    bf16x8 bfr[2][4];
#pragma unroll
    for (int nn = 0; nn < 2; ++nn) {
        int ecol = w * 32 + nn * 16 + c15;
#pragma unroll
        for (int ks = 0; ks < 4; ++ks)
            bfr[nn][ks] = *(const bf16x8*)(weT + ecol * 128 + ks * 32 + hi * 8);
    }

    // ---- staging decode: 4 f32x4 per thread, wave-contiguous 1KB loads ----
    // q = r*256 + t; di = q>>9; rowj = (q>>5)&15; qr = q&31
    const float* gp[4];
    int lo[4];
#pragma unroll
    for (int r = 0; r < 4; ++r) {
        int q = r * 256 + t;
        int di = q >> 9, rowj = (q >> 5) & 15, qr = q & 31;
        gp[r] = edge + (((size_t)(b * N_ + i0 + di)) * N_ + (j0 + rowj)) * E_ + qr * 4;
        lo[r] = di * 4096 + rowj * 256 + ((qr * 8) ^ ((rowj & 7) << 4));
    }
    const size_t tstep = (size_t)2 * N_ * E_;   // 2 i's per tile

    f32x4 ld[4];
#pragma unroll
    for (int r = 0; r < 4; ++r) ld[r] = *(const f32x4*)(gp[r]);   // tile 0

    float rmax[2][4];
#pragma unroll
    for (int nn = 0; nn < 2; ++nn)
#pragma unroll
        for (int rg = 0; rg < 4; ++rg) rmax[nn][rg] = -BIGN;

    for (int tt = 0; tt < NT; ++tt) {
        // barrier A: previous tile's ds_reads complete (buffer free)
        asm volatile("s_waitcnt lgkmcnt(0)" ::: "memory");
        __builtin_amdgcn_s_barrier();
        __builtin_amdgcn_sched_barrier(0);

        // stage: cvt staged regs -> swizzled LDS (compiler waits vmcnt for ld)
#pragma unroll
        for (int r = 0; r < 4; ++r) {
            uint2 s;
            s.x = cvt2(ld[r].x, ld[r].y);
            s.y = cvt2(ld[r].z, ld[r].w);
            *(uint2*)(atile + lo[r]) = s;
        }
        asm volatile("s_waitcnt lgkmcnt(0)" ::: "memory");
        __builtin_amdgcn_s_barrier();
        __builtin_amdgcn_sched_barrier(0);

        const int ib = b * N_ + i0 + 2 * tt;
        // epilogue operands FIRST (their vmcnt wait won't cover next loads)
        f32x4 aj0 = *(const f32x4*)(adj + (size_t)ib * N_ + j0 + hi * 4);
        f32x4 aj1 = *(const f32x4*)(adj + (size_t)(ib + 1) * N_ + j0 + hi * 4);
        float mv00 = m2g[(size_t)ib * 128 + w * 32 + c15];
        float mv01 = m2g[(size_t)ib * 128 + w * 32 + 16 + c15];
        float mv10 = m2g[(size_t)(ib + 1) * 128 + w * 32 + c15];
        float mv11 = m2g[(size_t)(ib + 1) * 128 + w * 32 + 16 + c15];
        // next tile's loads in flight across MFMA
        if (tt + 1 < NT) {
#pragma unroll
            for (int r = 0; r < 4; ++r)
                ld[r] = *(const f32x4*)(gp[r] + (size_t)(tt + 1) * tstep);
        }

        // ---- 2i x (16j x 32e) per wave: 16 MFMA from LDS A + reg B ----
        f32x4 acc[2][2] = {};
#pragma unroll
        for (int ks = 0; ks < 4; ++ks) {
            int ko = (ks * 64 + hi * 16) ^ ((c15 & 7) << 4);
            bf16x8 a0 = *(const bf16x8*)(atile + c15 * 256 + ko);
            bf16x8 a1 = *(const bf16x8*)(atile + 4096 + c15 * 256 + ko);
#pragma unroll
            for (int nn = 0; nn < 2; ++nn) {
                acc[0][nn] = __builtin_amdgcn_mfma_f32_16x16x32_bf16(
                    a0, bfr[nn][ks], acc[0][nn], 0, 0, 0);
                acc[1][nn] = __builtin_amdgcn_mfma_f32_16x16x32_bf16(
                    a1, bfr[nn][ks], acc[1][nn], 0, 0, 0);
            }
        }

        // ---- masked running max over the 2 i's ----
#pragma unroll
        for (int nn = 0; nn < 2; ++nn) {
            float m0 = nn ? mv01 : mv00;
            float m1 = nn ? mv11 : mv10;
#pragma unroll
            for (int rg = 0; rg < 4; ++rg) {
                float v0 = acc[0][nn][rg] + m0;
                v0 = (aj0[rg] > 0.0f) ? v0 : -BIGN;
                float v1 = acc[1][nn][rg] + m1;
                v1 = (aj1[rg] > 0.0f) ? v1 : -BIGN;
                rmax[nn][rg] = fmaxf(rmax[nn][rg], fmaxf(v0, v1));
            }
        }
    }

    // ---- waves own disjoint e-cols: write partials directly ----
    float* rp = redp + (size_t)blk * 2048;
#pragma unroll
    for (int nn = 0; nn < 2; ++nn)
#pragma unroll
        for (int rg = 0; rg < 4; ++rg)
            rp[(hi * 4 + rg) * 128 + w * 32 + nn * 16 + c15] = rmax[nn][rg];
}

// ---------------------------------------------------------------------------
// finish: red = max over ICS partials; out = relu(zo1 + (red+msg1+be)@Wo2+bo2)
// ---------------------------------------------------------------------------
__global__ __launch_bounds__(256) void finish_kernel(
    const float* __restrict__ redp, const float* __restrict__ msg1,
    const float* __restrict__ zo1, const float* __restrict__ be,
    const float* __restrict__ Wo2, const float* __restrict__ bo2,
    float* __restrict__ out, int icsbits)
{
    __shared__ float rb[8][128];
    const int t  = threadIdx.x;
    const int r0 = blockIdx.x * 8;
    const int S  = 1 << icsbits;

    for (int idx = t; idx < 1024; idx += 256) {
        int rr = idx >> 7, k = idx & 127;
        int r  = r0 + rr;
        int b  = r >> 8, j = r & 255;
        float v = -BIGN - 1.0f;
        for (int p = 0; p < S; ++p)
            v = fmaxf(v, redp[(size_t)((((b << icsbits) + p) << 4) + (j >> 4)) * 2048
                              + (j & 15) * 128 + k]);
        rb[rr][k] = v + msg1[(size_t)r * 128 + k] + be[k];
    }
    __syncthreads();

    const int col  = t & 127;
    const int half = t >> 7;
#pragma unroll
    for (int rx = 0; rx < 4; ++rx) {
        int rr = half * 4 + rx;
        size_t row = (size_t)(r0 + rr);
        float a = 0.0f;
#pragma unroll 8
        for (int k = 0; k < 128; ++k)
            a = fmaf(rb[rr][k], Wo2[k * 128 + col], a);
        float o = zo1[row * 128 + col] + bo2[col] + a;
        out[row * 128 + col] = fmaxf(o, 0.0f);
    }
}

extern "C" void kernel_launch(void* const* d_in, const int* in_sizes, int n_in,
                              void* d_out, int out_size, void* d_ws, size_t ws_size,
                              hipStream_t stream) {
    const float* node   = (const float*)d_in[0];
    const float* edge   = (const float*)d_in[1];
    const float* gf     = (const float*)d_in[2];
    const float* adj    = (const float*)d_in[3];
    const float* hidden = (const float*)d_in[4];
    const float* W1  = (const float*)d_in[5];
    const float* b1  = (const float*)d_in[6];
    const float* W2  = (const float*)d_in[7];
    const float* b2  = (const float*)d_in[8];
    const float* We  = (const float*)d_in[9];
    const float* be  = (const float*)d_in[10];
    const float* Wg  = (const float*)d_in[11];
    const float* bg  = (const float*)d_in[12];
    const float* Wo1 = (const float*)d_in[13];
    const float* bo1 = (const float*)d_in[14];
    const float* Wo2 = (const float*)d_in[15];
    const float* bo2 = (const float*)d_in[16];
    float* out = (float*)d_out;

    float* msg1 = (float*)d_ws;                                   // 1 MB
    float* m2g  = msg1 + 2048 * 128;                              // 1 MB
    float* zo1  = m2g + 2048 * 128;                               // 1 MB
    unsigned short* weT = (unsigned short*)(zo1 + 2048 * 128);    // 32 KB
    float* redp = (float*)((char*)weT + 128 * 128 * sizeof(unsigned short));

    // icsbits=4: 2048 blocks, redp 16MB. Fallback icsbits=3: 1024 blocks, 8MB.
    const size_t fixed = 3u * 1048576u + 32768u;
    int icsbits = (ws_size >= fixed + 17u * 1048576u) ? 4 : 3;
    int nblk    = (8 * 16) << icsbits;

    hipLaunchKernelGGL(prep_kernel, dim3(512), dim3(256), 0, stream,
                       node, hidden, gf, W1, b1, W2, b2, Wg, bg, Wo1, bo1, We,
                       msg1, m2g, zo1, weT);
    hipLaunchKernelGGL(pgn_main, dim3(nblk), dim3(256), 0, stream,
                       edge, adj, m2g, weT, redp, icsbits);
    hipLaunchKernelGGL(finish_kernel, dim3(256), dim3(256), 0, stream,
                       redp, msg1, zo1, be, Wo2, bo2, out, icsbits);
}